// Round 5
// baseline (404.052 us; speedup 1.0000x reference)
//
#include <hip/hip_runtime.h>

// MiniTransformer: B=131072, T=8, D=32, H=64, V=27  (all f32, out f32)
// R5: full prefix-output tables for t<=2 (27+729+19683 = 20439 prefixes,
//   2.2 MB, L2-resident) -> 37.5% of rows become a gather. Main compute
//   kernel covers t in [3,8) with t-major mapping (B=2^17 so t = idx>>17 is
//   free and wave-uniform). build_rows parallelized (was 1-block,
//   s_load-latency-bound, ~40 us). Falls back to R4 path if ws too small.

namespace {
constexpr int BTOT = 131072;     // 2^17
constexpr int T = 8;
constexpr int D = 32;
constexpr int H = 64;
constexpr int V = 27;
constexpr int NTOK = 27;
constexpr int NROW = T * NTOK;   // 216
constexpr float EPS = 1e-5f;

// ws layout (float offsets)
constexpr int WS_X  = 0;             // 216*32
constexpr int WS_Q  = 6912;
constexpr int WS_K  = 13824;
constexpr int WS_V  = 20736;
constexpr int WS_SC = 27648;         // 216*216 = 46656
constexpr int NSC   = NROW * NROW;
constexpr int WS_P  = WS_SC + NSC;   // 74304: prefix-output tables
constexpr int NPRE0 = 27;            // t=0 prefixes
constexpr int NPRE1 = 729;           // t=1
constexpr int NPRE2 = 19683;         // t=2
constexpr int NPRE  = NPRE0 + NPRE1 + NPRE2;   // 20439
constexpr size_t WS_NEED_BIG   = (size_t)(WS_P + NPRE * V) * 4;  // ~2.45 MB
constexpr size_t WS_NEED_SMALL = (size_t)WS_P * 4;
} // namespace

// ---- kernel A: X/Q/K/V row tables, thread per (row,d) ----
__global__ __launch_bounds__(256) void build_rows_kernel(
    const float* __restrict__ tokE, const float* __restrict__ posE,
    const float* __restrict__ Wq, const float* __restrict__ Wk,
    const float* __restrict__ Wv, float* __restrict__ ws) {
  const int idx = blockIdx.x * 256 + threadIdx.x;
  if (idx >= NROW * D) return;
  const int row = idx >> 5, d = idx & 31;
  const int t = row / NTOK, tok = row % NTOK;
  float x[D];
#pragma unroll
  for (int g = 0; g < D / 4; ++g) {
    const float4 a = *(const float4*)(tokE + tok * D + 4 * g);
    const float4 c = *(const float4*)(posE + t * D + 4 * g);
    x[4 * g + 0] = a.x + c.x;
    x[4 * g + 1] = a.y + c.y;
    x[4 * g + 2] = a.z + c.z;
    x[4 * g + 3] = a.w + c.w;
  }
  float aq = 0.f, ak = 0.f, av = 0.f;
#pragma unroll
  for (int k = 0; k < D; ++k) {
    const float xv = x[k];
    aq = fmaf(xv, Wq[k * D + d], aq);
    ak = fmaf(xv, Wk[k * D + d], ak);
    av = fmaf(xv, Wv[k * D + d], av);
  }
  ws[WS_X + row * D + d] = x[d];
  ws[WS_Q + row * D + d] = aq;
  ws[WS_K + row * D + d] = ak;
  ws[WS_V + row * D + d] = av;
}

// ---- kernel B: score table SC[(t*27+tokt)*216 + s*27+toks] ----
__global__ __launch_bounds__(256) void build_sc_kernel(float* __restrict__ ws) {
  const int i = blockIdx.x * 256 + threadIdx.x;
  if (i >= NSC) return;
  const int qrow = i / NROW;
  const int j    = i - qrow * NROW;
  const float4* q = (const float4*)(ws + WS_Q + qrow * D);
  const float4* k = (const float4*)(ws + WS_K + j * D);
  float a = 0.f;
#pragma unroll
  for (int g = 0; g < D / 4; ++g) {
    const float4 qa = q[g], ka = k[g];
    a = fmaf(qa.x, ka.x, a);
    a = fmaf(qa.y, ka.y, a);
    a = fmaf(qa.z, ka.z, a);
    a = fmaf(qa.w, ka.w, a);
  }
  ws[WS_SC + i] = a;
}

// ---- shared row computation: attention (from tables) + LN + MLP + LN + proj ----
__device__ __forceinline__ void compute_row(
    const int t, const int* toks,
    const float* __restrict__ ws,
    const float* __restrict__ W1, const float* __restrict__ W2,
    const float* __restrict__ Wo, float* __restrict__ dst) {
  const int tok_t = toks[t];
  const float* SC = ws + WS_SC + (t * NTOK + tok_t) * NROW;
  float sc[T];
#pragma unroll
  for (int s = 0; s < T; ++s)
    sc[s] = (s <= t) ? SC[s * NTOK + toks[s]] : -INFINITY;

  float mx = -INFINITY;
#pragma unroll
  for (int s = 0; s < T; ++s) mx = fmaxf(mx, sc[s]);
  float p[T];
  float den = 0.f;
#pragma unroll
  for (int s = 0; s < T; ++s) {
    p[s] = (s <= t) ? __expf(sc[s] - mx) : 0.f;
    den += p[s];
  }
  const float inv = 1.f / den;

  float o[D];
#pragma unroll
  for (int d = 0; d < D; ++d) o[d] = 0.f;
#pragma unroll
  for (int s = 0; s < T; ++s) {
    if (s <= t) {
      const float4* vr = (const float4*)(ws + WS_V + (s * NTOK + toks[s]) * D);
      const float ps = p[s];
#pragma unroll
      for (int g = 0; g < D / 4; ++g) {
        const float4 v4 = vr[g];
        o[4 * g + 0] = fmaf(ps, v4.x, o[4 * g + 0]);
        o[4 * g + 1] = fmaf(ps, v4.y, o[4 * g + 1]);
        o[4 * g + 2] = fmaf(ps, v4.z, o[4 * g + 2]);
        o[4 * g + 3] = fmaf(ps, v4.w, o[4 * g + 3]);
      }
    }
  }
  {
    const float4* xr = (const float4*)(ws + WS_X + (t * NTOK + tok_t) * D);
#pragma unroll
    for (int g = 0; g < D / 4; ++g) {
      const float4 x4 = xr[g];
      o[4 * g + 0] = fmaf(o[4 * g + 0], inv, x4.x);
      o[4 * g + 1] = fmaf(o[4 * g + 1], inv, x4.y);
      o[4 * g + 2] = fmaf(o[4 * g + 2], inv, x4.z);
      o[4 * g + 3] = fmaf(o[4 * g + 3], inv, x4.w);
    }
  }

  // LayerNorm 1
  {
    float s1 = 0.f;
#pragma unroll
    for (int d = 0; d < D; ++d) s1 += o[d];
    const float mean = s1 * (1.f / D);
    float s2 = 0.f;
#pragma unroll
    for (int d = 0; d < D; ++d) { const float c = o[d] - mean; s2 = fmaf(c, c, s2); }
    const float rr = rsqrtf(s2 * (1.f / D) + EPS);
#pragma unroll
    for (int d = 0; d < D; ++d) o[d] = (o[d] - mean) * rr;
  }

  // MLP
  float y[D];
#pragma unroll
  for (int d = 0; d < D; ++d) y[d] = 0.f;
#pragma unroll
  for (int jc = 0; jc < H / 16; ++jc) {
    float hh[16];
#pragma unroll
    for (int jj = 0; jj < 16; ++jj) {
      const int j = jc * 16 + jj;
      float a = 0.f;
#pragma unroll
      for (int d = 0; d < D; ++d) a = fmaf(o[d], W1[d * H + j], a);
      hh[jj] = fmaxf(a, 0.f);
    }
#pragma unroll
    for (int jj = 0; jj < 16; ++jj) {
      const int j = jc * 16 + jj;
#pragma unroll
      for (int d = 0; d < D; ++d) y[d] = fmaf(hh[jj], W2[j * D + d], y[d]);
    }
  }

  // residual + LayerNorm 2
#pragma unroll
  for (int d = 0; d < D; ++d) y[d] += o[d];
  {
    float s1 = 0.f;
#pragma unroll
    for (int d = 0; d < D; ++d) s1 += y[d];
    const float mean = s1 * (1.f / D);
    float s2 = 0.f;
#pragma unroll
    for (int d = 0; d < D; ++d) { const float c = y[d] - mean; s2 = fmaf(c, c, s2); }
    const float rr = rsqrtf(s2 * (1.f / D) + EPS);
#pragma unroll
    for (int d = 0; d < D; ++d) y[d] = (y[d] - mean) * rr;
  }

  // output projection
#pragma unroll
  for (int v = 0; v < V; ++v) {
    float a = 0.f;
#pragma unroll
    for (int d = 0; d < D; ++d) a = fmaf(y[d], Wo[d * V + v], a);
    dst[v] = a;
  }
}

// ---- kernel P: prefix-output tables for t<=2 ----
__global__ __launch_bounds__(256) void build_prefix_kernel(
    float* __restrict__ ws,
    const float* __restrict__ W1, const float* __restrict__ W2,
    const float* __restrict__ Wo) {
  const int i = blockIdx.x * 256 + threadIdx.x;
  if (i >= NPRE) return;
  int t, p;
  if (i < NPRE0)              { t = 0; p = i; }
  else if (i < NPRE0 + NPRE1) { t = 1; p = i - NPRE0; }
  else                        { t = 2; p = i - NPRE0 - NPRE1; }
  int toks[T] = {0, 0, 0, 0, 0, 0, 0, 0};
  if (t == 0) { toks[0] = p; }
  else if (t == 1) { toks[0] = p / 27; toks[1] = p % 27; }
  else { toks[0] = p / 729; const int r = p % 729; toks[1] = r / 27; toks[2] = r % 27; }
  compute_row(t, toks, ws, W1, W2, Wo, ws + WS_P + i * V);
}

// ---- kernel G: gather t<=2 rows from tables; thread per (b, j) ----
__global__ __launch_bounds__(256) void gather_kernel(
    const int* __restrict__ tokens,
    const float* __restrict__ ws,
    float* __restrict__ out) {
  const int idx = blockIdx.x * 256 + threadIdx.x;   // [0, BTOT*27), exact
  const int j = idx % V;
  const int b = idx / V;
  const int t0 = tokens[b * T + 0];
  const int t1 = tokens[b * T + 1];
  const int t2 = tokens[b * T + 2];
  const int p0 = t0;
  const int p1 = t0 * 27 + t1;
  const int p2 = p1 * 27 + t2;
  const long long ob = (long long)b * T * V;
  out[ob + 0 * V + j] = ws[WS_P + p0 * V + j];
  out[ob + 1 * V + j] = ws[WS_P + (NPRE0 + p1) * V + j];
  out[ob + 2 * V + j] = ws[WS_P + (NPRE0 + NPRE1 + p2) * V + j];
}

// ---- kernel C: main compute for t in [3,8), t-major ----
__global__ __launch_bounds__(256) void mini_kernel_tmajor(
    const int* __restrict__ tokens,
    const float* __restrict__ ws,
    const float* __restrict__ W1, const float* __restrict__ W2,
    const float* __restrict__ Wo, float* __restrict__ out) {
  const int idx = blockIdx.x * 256 + threadIdx.x;   // [0, 5*BTOT), exact
  const int t = 3 + (idx >> 17);                    // wave-uniform (BTOT=2^17)
  const int b = idx & (BTOT - 1);
  const int4 ta = *(const int4*)(tokens + b * T);
  const int4 tb = *(const int4*)(tokens + b * T + 4);
  int toks[T];
  toks[0] = ta.x; toks[1] = ta.y; toks[2] = ta.z; toks[3] = ta.w;
  toks[4] = tb.x; toks[5] = tb.y; toks[6] = tb.z; toks[7] = tb.w;
  compute_row(t, toks, ws, W1, W2, Wo, out + (long long)(b * T + t) * V);
}

// ---- fallback (R4-style): all rows, r-major ----
__global__ __launch_bounds__(256) void mini_kernel_all(
    const int* __restrict__ tokens,
    const float* __restrict__ ws,
    const float* __restrict__ W1, const float* __restrict__ W2,
    const float* __restrict__ Wo, float* __restrict__ out) {
  const int r = blockIdx.x * 256 + threadIdx.x;
  const int b = r >> 3;
  const int t = r & 7;
  const int4 ta = *(const int4*)(tokens + b * T);
  const int4 tb = *(const int4*)(tokens + b * T + 4);
  int toks[T];
  toks[0] = ta.x; toks[1] = ta.y; toks[2] = ta.z; toks[3] = ta.w;
  toks[4] = tb.x; toks[5] = tb.y; toks[6] = tb.z; toks[7] = tb.w;
  compute_row(t, toks, ws, W1, W2, Wo, out + (long long)r * V);
}

extern "C" void kernel_launch(void* const* d_in, const int* in_sizes, int n_in,
                              void* d_out, int out_size, void* d_ws, size_t ws_size,
                              hipStream_t stream) {
  const int*   tokens  = (const int*)d_in[0];
  const float* tok_emb = (const float*)d_in[1];
  const float* pos_emb = (const float*)d_in[2];
  const float* Wq      = (const float*)d_in[3];
  const float* Wk      = (const float*)d_in[4];
  const float* Wv      = (const float*)d_in[5];
  const float* W1      = (const float*)d_in[6];
  const float* W2      = (const float*)d_in[7];
  const float* Wout    = (const float*)d_in[8];
  float* ws = (float*)d_ws;
  float* out = (float*)d_out;

  hipLaunchKernelGGL(build_rows_kernel, dim3((NROW * D + 255) / 256), dim3(256), 0,
                     stream, tok_emb, pos_emb, Wq, Wk, Wv, ws);
  hipLaunchKernelGGL(build_sc_kernel, dim3((NSC + 255) / 256), dim3(256), 0, stream, ws);

  if (ws_size >= WS_NEED_BIG) {
    hipLaunchKernelGGL(build_prefix_kernel, dim3((NPRE + 255) / 256), dim3(256), 0,
                       stream, ws, W1, W2, Wout);
    hipLaunchKernelGGL(gather_kernel, dim3((BTOT * V) / 256), dim3(256), 0, stream,
                       tokens, ws, out);
    hipLaunchKernelGGL(mini_kernel_tmajor, dim3((5 * BTOT) / 256), dim3(256), 0,
                       stream, tokens, ws, W1, W2, Wout, out);
  } else {
    hipLaunchKernelGGL(mini_kernel_all, dim3((BTOT * T) / 256), dim3(256), 0,
                       stream, tokens, ws, W1, W2, Wout, out);
  }
}

// Round 6
// 366.299 us; speedup vs baseline: 1.1031x; 1.1031x over previous
//
#include <hip/hip_runtime.h>

// MiniTransformer: B=131072, T=8, D=32, H=64, V=27  (all f32, out f32)
// R6: same math as R5; launch restructure only.
//   R5 post-mortem: main kernel 280->192 us but total flat — build_prefix
//   (80 blocks, latency-bound, ~30-50 us) + gather + 5 launches ate it.
//   Fix: fuse build_prefix blocks INTO the t>=3 compute kernel (independent
//   work, block-uniform branch) so the prefix table builds in the shadow of
//   the 2560-block main grid. Gather (depends on prefix table) stays separate.

namespace {
constexpr int BTOT = 131072;     // 2^17
constexpr int T = 8;
constexpr int D = 32;
constexpr int H = 64;
constexpr int V = 27;
constexpr int NTOK = 27;
constexpr int NROW = T * NTOK;   // 216
constexpr float EPS = 1e-5f;

// ws layout (float offsets)
constexpr int WS_X  = 0;             // 216*32
constexpr int WS_Q  = 6912;
constexpr int WS_K  = 13824;
constexpr int WS_V  = 20736;
constexpr int WS_SC = 27648;         // 216*216 = 46656
constexpr int NSC   = NROW * NROW;
constexpr int WS_P  = WS_SC + NSC;   // 74304: prefix-output tables
constexpr int NPRE0 = 27;
constexpr int NPRE1 = 729;
constexpr int NPRE2 = 19683;
constexpr int NPRE  = NPRE0 + NPRE1 + NPRE2;   // 20439
constexpr size_t WS_NEED_BIG = (size_t)(WS_P + NPRE * V) * 4;  // ~2.45 MB

constexpr int MAIN_BLOCKS = (5 * BTOT) / 256;          // 2560, exact
constexpr int PRE_BLOCKS  = (NPRE + 255) / 256;        // 80
} // namespace

// ---- kernel A: X/Q/K/V row tables, thread per (row,d) ----
__global__ __launch_bounds__(256) void build_rows_kernel(
    const float* __restrict__ tokE, const float* __restrict__ posE,
    const float* __restrict__ Wq, const float* __restrict__ Wk,
    const float* __restrict__ Wv, float* __restrict__ ws) {
  const int idx = blockIdx.x * 256 + threadIdx.x;
  if (idx >= NROW * D) return;
  const int row = idx >> 5, d = idx & 31;
  const int t = row / NTOK, tok = row % NTOK;
  float x[D];
#pragma unroll
  for (int g = 0; g < D / 4; ++g) {
    const float4 a = *(const float4*)(tokE + tok * D + 4 * g);
    const float4 c = *(const float4*)(posE + t * D + 4 * g);
    x[4 * g + 0] = a.x + c.x;
    x[4 * g + 1] = a.y + c.y;
    x[4 * g + 2] = a.z + c.z;
    x[4 * g + 3] = a.w + c.w;
  }
  float aq = 0.f, ak = 0.f, av = 0.f;
#pragma unroll
  for (int k = 0; k < D; ++k) {
    const float xv = x[k];
    aq = fmaf(xv, Wq[k * D + d], aq);
    ak = fmaf(xv, Wk[k * D + d], ak);
    av = fmaf(xv, Wv[k * D + d], av);
  }
  ws[WS_X + row * D + d] = x[d];
  ws[WS_Q + row * D + d] = aq;
  ws[WS_K + row * D + d] = ak;
  ws[WS_V + row * D + d] = av;
}

// ---- kernel B: score table SC[(t*27+tokt)*216 + s*27+toks] ----
__global__ __launch_bounds__(256) void build_sc_kernel(float* __restrict__ ws) {
  const int i = blockIdx.x * 256 + threadIdx.x;
  if (i >= NSC) return;
  const int qrow = i / NROW;
  const int j    = i - qrow * NROW;
  const float4* q = (const float4*)(ws + WS_Q + qrow * D);
  const float4* k = (const float4*)(ws + WS_K + j * D);
  float a = 0.f;
#pragma unroll
  for (int g = 0; g < D / 4; ++g) {
    const float4 qa = q[g], ka = k[g];
    a = fmaf(qa.x, ka.x, a);
    a = fmaf(qa.y, ka.y, a);
    a = fmaf(qa.z, ka.z, a);
    a = fmaf(qa.w, ka.w, a);
  }
  ws[WS_SC + i] = a;
}

// ---- shared row computation ----
__device__ __forceinline__ void compute_row(
    const int t, const int* toks,
    const float* __restrict__ ws,
    const float* __restrict__ W1, const float* __restrict__ W2,
    const float* __restrict__ Wo, float* __restrict__ dst) {
  const int tok_t = toks[t];
  const float* SC = ws + WS_SC + (t * NTOK + tok_t) * NROW;
  float sc[T];
#pragma unroll
  for (int s = 0; s < T; ++s)
    sc[s] = (s <= t) ? SC[s * NTOK + toks[s]] : -INFINITY;

  float mx = -INFINITY;
#pragma unroll
  for (int s = 0; s < T; ++s) mx = fmaxf(mx, sc[s]);
  float p[T];
  float den = 0.f;
#pragma unroll
  for (int s = 0; s < T; ++s) {
    p[s] = (s <= t) ? __expf(sc[s] - mx) : 0.f;
    den += p[s];
  }
  const float inv = 1.f / den;

  float o[D];
#pragma unroll
  for (int d = 0; d < D; ++d) o[d] = 0.f;
#pragma unroll
  for (int s = 0; s < T; ++s) {
    if (s <= t) {
      const float4* vr = (const float4*)(ws + WS_V + (s * NTOK + toks[s]) * D);
      const float ps = p[s];
#pragma unroll
      for (int g = 0; g < D / 4; ++g) {
        const float4 v4 = vr[g];
        o[4 * g + 0] = fmaf(ps, v4.x, o[4 * g + 0]);
        o[4 * g + 1] = fmaf(ps, v4.y, o[4 * g + 1]);
        o[4 * g + 2] = fmaf(ps, v4.z, o[4 * g + 2]);
        o[4 * g + 3] = fmaf(ps, v4.w, o[4 * g + 3]);
      }
    }
  }
  {
    const float4* xr = (const float4*)(ws + WS_X + (t * NTOK + tok_t) * D);
#pragma unroll
    for (int g = 0; g < D / 4; ++g) {
      const float4 x4 = xr[g];
      o[4 * g + 0] = fmaf(o[4 * g + 0], inv, x4.x);
      o[4 * g + 1] = fmaf(o[4 * g + 1], inv, x4.y);
      o[4 * g + 2] = fmaf(o[4 * g + 2], inv, x4.z);
      o[4 * g + 3] = fmaf(o[4 * g + 3], inv, x4.w);
    }
  }

  // LayerNorm 1
  {
    float s1 = 0.f;
#pragma unroll
    for (int d = 0; d < D; ++d) s1 += o[d];
    const float mean = s1 * (1.f / D);
    float s2 = 0.f;
#pragma unroll
    for (int d = 0; d < D; ++d) { const float c = o[d] - mean; s2 = fmaf(c, c, s2); }
    const float rr = rsqrtf(s2 * (1.f / D) + EPS);
#pragma unroll
    for (int d = 0; d < D; ++d) o[d] = (o[d] - mean) * rr;
  }

  // MLP
  float y[D];
#pragma unroll
  for (int d = 0; d < D; ++d) y[d] = 0.f;
#pragma unroll
  for (int jc = 0; jc < H / 16; ++jc) {
    float hh[16];
#pragma unroll
    for (int jj = 0; jj < 16; ++jj) {
      const int j = jc * 16 + jj;
      float a = 0.f;
#pragma unroll
      for (int d = 0; d < D; ++d) a = fmaf(o[d], W1[d * H + j], a);
      hh[jj] = fmaxf(a, 0.f);
    }
#pragma unroll
    for (int jj = 0; jj < 16; ++jj) {
      const int j = jc * 16 + jj;
#pragma unroll
      for (int d = 0; d < D; ++d) y[d] = fmaf(hh[jj], W2[j * D + d], y[d]);
    }
  }

  // residual + LayerNorm 2
#pragma unroll
  for (int d = 0; d < D; ++d) y[d] += o[d];
  {
    float s1 = 0.f;
#pragma unroll
    for (int d = 0; d < D; ++d) s1 += y[d];
    const float mean = s1 * (1.f / D);
    float s2 = 0.f;
#pragma unroll
    for (int d = 0; d < D; ++d) { const float c = y[d] - mean; s2 = fmaf(c, c, s2); }
    const float rr = rsqrtf(s2 * (1.f / D) + EPS);
#pragma unroll
    for (int d = 0; d < D; ++d) y[d] = (y[d] - mean) * rr;
  }

  // output projection
#pragma unroll
  for (int v = 0; v < V; ++v) {
    float a = 0.f;
#pragma unroll
    for (int d = 0; d < D; ++d) a = fmaf(y[d], Wo[d * V + v], a);
    dst[v] = a;
  }
}

// ---- kernel C: fused main (t in [3,8), t-major) + prefix-table build ----
__global__ __launch_bounds__(256) void fused_main_kernel(
    const int* __restrict__ tokens,
    float* __restrict__ ws,
    const float* __restrict__ W1, const float* __restrict__ W2,
    const float* __restrict__ Wo, float* __restrict__ out) {
  if (blockIdx.x < MAIN_BLOCKS) {
    const int idx = blockIdx.x * 256 + threadIdx.x;   // [0, 5*BTOT), exact
    const int t = 3 + (idx >> 17);                    // wave-uniform (BTOT=2^17)
    const int b = idx & (BTOT - 1);
    const int4 ta = *(const int4*)(tokens + b * T);
    const int4 tb = *(const int4*)(tokens + b * T + 4);
    int toks[T];
    toks[0] = ta.x; toks[1] = ta.y; toks[2] = ta.z; toks[3] = ta.w;
    toks[4] = tb.x; toks[5] = tb.y; toks[6] = tb.z; toks[7] = tb.w;
    compute_row(t, toks, ws, W1, W2, Wo, out + (long long)(b * T + t) * V);
  } else {
    const int i = (blockIdx.x - MAIN_BLOCKS) * 256 + threadIdx.x;
    if (i >= NPRE) return;
    int t, p;
    if (i < NPRE0)              { t = 0; p = i; }
    else if (i < NPRE0 + NPRE1) { t = 1; p = i - NPRE0; }
    else                        { t = 2; p = i - NPRE0 - NPRE1; }
    int toks[T] = {0, 0, 0, 0, 0, 0, 0, 0};
    if (t == 0) { toks[0] = p; }
    else if (t == 1) { toks[0] = p / 27; toks[1] = p % 27; }
    else { toks[0] = p / 729; const int r = p % 729; toks[1] = r / 27; toks[2] = r % 27; }
    compute_row(t, toks, ws, W1, W2, Wo, ws + WS_P + i * V);
  }
}

// ---- kernel G: gather t<=2 rows from tables; thread per (b, j) ----
__global__ __launch_bounds__(256) void gather_kernel(
    const int* __restrict__ tokens,
    const float* __restrict__ ws,
    float* __restrict__ out) {
  const int idx = blockIdx.x * 256 + threadIdx.x;   // [0, BTOT*27), exact
  const int j = idx % V;
  const int b = idx / V;
  const int t0 = tokens[b * T + 0];
  const int t1 = tokens[b * T + 1];
  const int t2 = tokens[b * T + 2];
  const int p0 = t0;
  const int p1 = t0 * 27 + t1;
  const int p2 = p1 * 27 + t2;
  const long long ob = (long long)b * T * V;
  out[ob + 0 * V + j] = ws[WS_P + p0 * V + j];
  out[ob + 1 * V + j] = ws[WS_P + (NPRE0 + p1) * V + j];
  out[ob + 2 * V + j] = ws[WS_P + (NPRE0 + NPRE1 + p2) * V + j];
}

// ---- fallback (R4-style): all rows, r-major ----
__global__ __launch_bounds__(256) void mini_kernel_all(
    const int* __restrict__ tokens,
    const float* __restrict__ ws,
    const float* __restrict__ W1, const float* __restrict__ W2,
    const float* __restrict__ Wo, float* __restrict__ out) {
  const int r = blockIdx.x * 256 + threadIdx.x;
  const int b = r >> 3;
  const int t = r & 7;
  const int4 ta = *(const int4*)(tokens + b * T);
  const int4 tb = *(const int4*)(tokens + b * T + 4);
  int toks[T];
  toks[0] = ta.x; toks[1] = ta.y; toks[2] = ta.z; toks[3] = ta.w;
  toks[4] = tb.x; toks[5] = tb.y; toks[6] = tb.z; toks[7] = tb.w;
  compute_row(t, toks, ws, W1, W2, Wo, out + (long long)r * V);
}

extern "C" void kernel_launch(void* const* d_in, const int* in_sizes, int n_in,
                              void* d_out, int out_size, void* d_ws, size_t ws_size,
                              hipStream_t stream) {
  const int*   tokens  = (const int*)d_in[0];
  const float* tok_emb = (const float*)d_in[1];
  const float* pos_emb = (const float*)d_in[2];
  const float* Wq      = (const float*)d_in[3];
  const float* Wk      = (const float*)d_in[4];
  const float* Wv      = (const float*)d_in[5];
  const float* W1      = (const float*)d_in[6];
  const float* W2      = (const float*)d_in[7];
  const float* Wout    = (const float*)d_in[8];
  float* ws = (float*)d_ws;
  float* out = (float*)d_out;

  hipLaunchKernelGGL(build_rows_kernel, dim3((NROW * D + 255) / 256), dim3(256), 0,
                     stream, tok_emb, pos_emb, Wq, Wk, Wv, ws);
  hipLaunchKernelGGL(build_sc_kernel, dim3((NSC + 255) / 256), dim3(256), 0, stream, ws);

  if (ws_size >= WS_NEED_BIG) {
    hipLaunchKernelGGL(fused_main_kernel, dim3(MAIN_BLOCKS + PRE_BLOCKS), dim3(256), 0,
                       stream, tokens, ws, W1, W2, Wout, out);
    hipLaunchKernelGGL(gather_kernel, dim3((BTOT * V) / 256), dim3(256), 0, stream,
                       tokens, ws, out);
  } else {
    hipLaunchKernelGGL(mini_kernel_all, dim3((BTOT * T) / 256), dim3(256), 0,
                       stream, tokens, ws, W1, W2, Wout, out);
  }
}